// Round 2
// baseline (3119.052 us; speedup 1.0000x reference)
//
#include <hip/hip_runtime.h>
#include <cmath>

typedef __attribute__((ext_vector_type(8))) short short8v;
typedef __attribute__((ext_vector_type(4))) float float4v;
typedef __attribute__((ext_vector_type(2))) unsigned int u32x2;
typedef unsigned short u16;
typedef unsigned int u32;

__device__ __forceinline__ float b2f(u16 s) {
  union { u32 u; float f; } v; v.u = ((u32)s) << 16; return v.f;
}
__device__ __forceinline__ u16 f2b(float f) {
  union { float f; u32 u; } v; v.f = f;
  return (u16)((v.u + 0x7fffu + ((v.u >> 16) & 1u)) >> 16);
}

// ---------------- CSR build ----------------
__global__ __launch_bounds__(256) void hist_kernel(const int* __restrict__ rows,
                                                   int* __restrict__ cnt, int E) {
  int i = blockIdx.x * 256 + threadIdx.x;
  if (i < E) atomicAdd(&cnt[rows[i]], 1);
}

// in-place: data[i] (counts) -> exclusive-within-block; bsum[b] = block total
__global__ __launch_bounds__(1024) void scanA_kernel(int* __restrict__ data,
                                                     int* __restrict__ bsum, int n) {
  __shared__ int sd[1024];
  int tid = threadIdx.x;
  int i = blockIdx.x * 1024 + tid;
  int v = (i < n) ? data[i] : 0;
  sd[tid] = v;
  __syncthreads();
  for (int o = 1; o < 1024; o <<= 1) {
    int t = (tid >= o) ? sd[tid - o] : 0;
    __syncthreads();
    sd[tid] += t;
    __syncthreads();
  }
  if (i < n) data[i] = sd[tid] - v;
  if (tid == 1023) bsum[blockIdx.x] = sd[1023];
}

// single wave: exclusive scan of nb (<=64) block sums; *total_out = grand total
__global__ __launch_bounds__(64) void scanB_kernel(int* __restrict__ bsum, int nb,
                                                   int* __restrict__ total_out) {
  int lane = threadIdx.x;
  int v = (lane < nb) ? bsum[lane] : 0;
  int orig = v;
  for (int o = 1; o < 64; o <<= 1) {
    int t = __shfl_up(v, o, 64);
    if (lane >= o) v += t;
  }
  if (lane < nb) bsum[lane] = v - orig;
  if (lane == 63) *total_out = v;
}

__global__ __launch_bounds__(256) void scanC_kernel(int* __restrict__ cursor,
                                                    const int* __restrict__ bsum,
                                                    int* __restrict__ rowptr, int n) {
  int i = blockIdx.x * 256 + threadIdx.x;
  if (i >= n) return;
  int val = cursor[i] + bsum[i >> 10];
  rowptr[i] = val;
  cursor[i] = val;
}

// pack (w as u16 fixed point, col as u16) into one u32 per edge
__global__ __launch_bounds__(256) void scatter_kernel(const int* __restrict__ rows,
                                                      const int* __restrict__ cols,
                                                      const float* __restrict__ ew,
                                                      int* __restrict__ cursor,
                                                      u32* __restrict__ pe, int E) {
  int i = blockIdx.x * 256 + threadIdx.x;
  if (i >= E) return;
  int p = atomicAdd(&cursor[rows[i]], 1);
  u32 wq = (u32)(ew[i] * 65536.0f);
  if (wq > 65535u) wq = 65535u;
  pe[p] = (wq << 16) | (u32)cols[i];
}

// ---------------- conversions ----------------
// W1 [N,256] f32 -> panel-major bf16 [8][N][32]
__global__ __launch_bounds__(256) void cvt_w1_kernel(const float* __restrict__ in,
                                                     u16* __restrict__ outb, int n, int N32) {
  int tid = blockIdx.x * 256 + threadIdx.x;
  if (tid >= n * 8) return;
  int node = tid >> 3, q = tid & 7, panel = blockIdx.y;
  float4 v = *(const float4*)(in + (size_t)node * 256 + panel * 32 + q * 4);
  u32x2 o;
  o.x = (u32)f2b(v.x) | ((u32)f2b(v.y) << 16);
  o.y = (u32)f2b(v.z) | ((u32)f2b(v.w) << 16);
  *(u32x2*)(outb + (size_t)panel * N32 + (size_t)node * 32 + q * 4) = o;
}

// B'[l][n][k] = bf16( theta_l * Wc[l][k][n] + (1-theta_l)*(k==n) )
__global__ __launch_bounds__(256) void cvt_wc_kernel(const float* __restrict__ in,
                                                     u16* __restrict__ outb, int total) {
  int i = blockIdx.x * 256 + threadIdx.x;
  if (i >= total) return;
  int l = i >> 16; int r = i & 65535; int n = r >> 8; int k = r & 255;
  float theta = logf(0.1f / (float)(l + 1) + 1.0f);
  float v = theta * in[(l << 16) + (k << 8) + n];
  if (k == n) v += 1.0f - theta;
  outb[i] = f2b(v);
}

// ---------------- panel SpMM ----------------
// one wave per dest row per panel; 8 edge slots x 8 col-quad lanes
__global__ __launch_bounds__(256) void spmm1_kernel(const int* __restrict__ rowptr,
                                                    const u32* __restrict__ pe,
                                                    const u16* __restrict__ Xp,
                                                    u16* __restrict__ outp,
                                                    int n, int N32) {
  int row = blockIdx.x * 4 + (threadIdx.x >> 6);
  if (row >= n) return;
  int lane = threadIdx.x & 63;
  int slot = lane >> 3, cq = lane & 7;
  const u16* Xpp = Xp + (size_t)blockIdx.y * N32;
  int s = rowptr[row], e = rowptr[row + 1];
  float a0 = 0, a1 = 0, a2 = 0, a3 = 0;
  for (int j = s + slot; j < e; j += 8) {
    u32 p = __builtin_nontemporal_load(pe + j);
    float wv = (float)(p >> 16) * (1.0f / 65536.0f);
    int c = (int)(p & 0xFFFFu);
    u32x2 v = *(const u32x2*)(Xpp + ((size_t)c << 5) + (cq << 2));
    a0 = fmaf(wv, b2f((u16)(v.x & 0xffffu)), a0);
    a1 = fmaf(wv, b2f((u16)(v.x >> 16)), a1);
    a2 = fmaf(wv, b2f((u16)(v.y & 0xffffu)), a2);
    a3 = fmaf(wv, b2f((u16)(v.y >> 16)), a3);
  }
  for (int m = 8; m < 64; m <<= 1) {
    a0 += __shfl_xor(a0, m); a1 += __shfl_xor(a1, m);
    a2 += __shfl_xor(a2, m); a3 += __shfl_xor(a3, m);
  }
  if (lane < 8) {
    u32x2 o;
    o.x = (u32)f2b(fmaxf(a0, 0.f)) | ((u32)f2b(fmaxf(a1, 0.f)) << 16);
    o.y = (u32)f2b(fmaxf(a2, 0.f)) | ((u32)f2b(fmaxf(a3, 0.f)) << 16);
    __builtin_nontemporal_store(o, (u32x2*)(outp + (size_t)blockIdx.y * N32 + ((size_t)row << 5) + (lane << 2)));
  }
}

// support = 0.9*spmm(h) + 0.1*anchor   (all panel-major)
__global__ __launch_bounds__(256) void spmm_blend_kernel(const int* __restrict__ rowptr,
                                                         const u32* __restrict__ pe,
                                                         const u16* __restrict__ Xp,
                                                         const u16* __restrict__ anchor,
                                                         u16* __restrict__ outp,
                                                         int n, int N32) {
  int row = blockIdx.x * 4 + (threadIdx.x >> 6);
  if (row >= n) return;
  int lane = threadIdx.x & 63;
  int slot = lane >> 3, cq = lane & 7;
  const u16* Xpp = Xp + (size_t)blockIdx.y * N32;
  int s = rowptr[row], e = rowptr[row + 1];
  float a0 = 0, a1 = 0, a2 = 0, a3 = 0;
  for (int j = s + slot; j < e; j += 8) {
    u32 p = __builtin_nontemporal_load(pe + j);
    float wv = (float)(p >> 16) * (1.0f / 65536.0f);
    int c = (int)(p & 0xFFFFu);
    u32x2 v = *(const u32x2*)(Xpp + ((size_t)c << 5) + (cq << 2));
    a0 = fmaf(wv, b2f((u16)(v.x & 0xffffu)), a0);
    a1 = fmaf(wv, b2f((u16)(v.x >> 16)), a1);
    a2 = fmaf(wv, b2f((u16)(v.y & 0xffffu)), a2);
    a3 = fmaf(wv, b2f((u16)(v.y >> 16)), a3);
  }
  for (int m = 8; m < 64; m <<= 1) {
    a0 += __shfl_xor(a0, m); a1 += __shfl_xor(a1, m);
    a2 += __shfl_xor(a2, m); a3 += __shfl_xor(a3, m);
  }
  if (lane < 8) {
    size_t off = (size_t)blockIdx.y * N32 + ((size_t)row << 5) + (lane << 2);
    u32x2 av = __builtin_nontemporal_load((const u32x2*)(anchor + off));
    float r0 = 0.9f * a0 + 0.1f * b2f((u16)(av.x & 0xffffu));
    float r1 = 0.9f * a1 + 0.1f * b2f((u16)(av.x >> 16));
    float r2 = 0.9f * a2 + 0.1f * b2f((u16)(av.y & 0xffffu));
    float r3 = 0.9f * a3 + 0.1f * b2f((u16)(av.y >> 16));
    u32x2 o;
    o.x = (u32)f2b(r0) | ((u32)f2b(r1) << 16);
    o.y = (u32)f2b(r2) | ((u32)f2b(r3) << 16);
    __builtin_nontemporal_store(o, (u32x2*)(outp + off));
  }
}

// ---------------- dense GEMM: Hout = relu(A @ B'), panel-major A and Hout ----------------
__global__ __launch_bounds__(128) void gemm_kernel(const u16* __restrict__ A,
                                                   const u16* __restrict__ B,
                                                   u16* __restrict__ Hout, int N32) {
  int wave = threadIdx.x >> 6;
  int lane = threadIdx.x & 63;
  int m0 = blockIdx.x * 64 + wave * 32;
  int r0 = m0 + (lane & 15);
  int khalf = (lane >> 4) << 3;
  const u16* Ap = A + (size_t)r0 * 32 + khalf;
  const u16* Bp = B + ((lane & 15) << 8) + khalf;

  float4v acc0[16], acc1[16];
#pragma unroll
  for (int i = 0; i < 16; ++i) {
    acc0[i] = (float4v){0.f, 0.f, 0.f, 0.f};
    acc1[i] = (float4v){0.f, 0.f, 0.f, 0.f};
  }

  for (int ks = 0; ks < 8; ++ks) {
    short8v a0 = __builtin_nontemporal_load((const short8v*)(Ap + (size_t)ks * N32));
    short8v a1 = __builtin_nontemporal_load((const short8v*)(Ap + (size_t)ks * N32 + 512));
#pragma unroll
    for (int nf = 0; nf < 16; ++nf) {
      short8v b = *(const short8v*)(Bp + (nf << 12) + (ks << 5));
      acc0[nf] = __builtin_amdgcn_mfma_f32_16x16x32_bf16(a0, b, acc0[nf], 0, 0, 0);
      acc1[nf] = __builtin_amdgcn_mfma_f32_16x16x32_bf16(a1, b, acc1[nf], 0, 0, 0);
    }
  }

  int rbase = m0 + ((lane >> 4) << 2);
  int ccol = lane & 15;
#pragma unroll
  for (int nf = 0; nf < 16; ++nf) {
    size_t cbase = (size_t)(nf >> 1) * N32 + ((nf & 1) << 4) + ccol;
#pragma unroll
    for (int j = 0; j < 4; ++j) {
      int r = rbase + j;
      __builtin_nontemporal_store(f2b(fmaxf(acc0[nf][j], 0.f)),
                                  Hout + cbase + (size_t)r * 32);
      __builtin_nontemporal_store(f2b(fmaxf(acc1[nf][j], 0.f)),
                                  Hout + cbase + (size_t)(r + 16) * 32);
    }
  }
}

// ---------------- h @ W2 (256 -> 10), h panel-major ----------------
__global__ __launch_bounds__(256) void gemm2_kernel(const u16* __restrict__ Hb,
                                                    const float* __restrict__ W2,
                                                    float* __restrict__ g, int n, int N32) {
  int idx = blockIdx.x * 256 + threadIdx.x;
  if (idx >= n * 10) return;
  int r = idx / 10, c = idx - r * 10;
  float acc = 0.f;
  for (int p = 0; p < 8; ++p) {
    const u16* bp = Hb + (size_t)p * N32 + (size_t)r * 32;
    const float* wp = W2 + p * 320 + c;
#pragma unroll
    for (int q = 0; q < 32; ++q) acc = fmaf(b2f(bp[q]), wp[q * 10], acc);
  }
  g[idx] = acc;
}

// ---------------- final SpMM on [N,10] f32 ----------------
__global__ __launch_bounds__(256) void spmm_final_kernel(const int* __restrict__ rowptr,
                                                         const u32* __restrict__ pe,
                                                         const float* __restrict__ g,
                                                         float* __restrict__ out, int n) {
  int row = blockIdx.x * 4 + (threadIdx.x >> 6);
  if (row >= n) return;
  int lane = threadIdx.x & 63;
  int es = lane / 10;
  int c = lane - es * 10;
  int s = rowptr[row], e = rowptr[row + 1];
  float acc = 0.f;
  if (lane < 60) {
    for (int j = s + es; j < e; j += 6) {
      u32 p = __builtin_nontemporal_load(pe + j);
      float wv = (float)(p >> 16) * (1.0f / 65536.0f);
      acc = fmaf(wv, g[(size_t)(p & 0xFFFFu) * 10 + c], acc);
    }
  }
  float a0 = acc;
  acc = a0 + __shfl(a0, lane + 10, 64) + __shfl(a0, lane + 20, 64) +
        __shfl(a0, lane + 30, 64) + __shfl(a0, lane + 40, 64) + __shfl(a0, lane + 50, 64);
  if (lane < 10) out[(size_t)row * 10 + lane] = acc;
}

extern "C" void kernel_launch(void* const* d_in, const int* in_sizes, int n_in,
                              void* d_out, int out_size, void* d_ws, size_t ws_size,
                              hipStream_t stream) {
  const int* rows = (const int*)d_in[1];
  const int* cols = (const int*)d_in[2];
  const float* ew = (const float*)d_in[3];
  const float* W1 = (const float*)d_in[4];
  const float* Wc = (const float*)d_in[5];
  const float* W2 = (const float*)d_in[6];
  float* out = (float*)d_out;
  const int N = in_sizes[0];
  const int E = in_sizes[1];
  const int L = in_sizes[5] >> 16;
  const int NP = ((N + 127) / 128) * 128;  // padded rows (multiple of 64-row gemm blocks)
  const int N32 = NP * 32;                 // u16 elements per feature panel

  char* w = (char*)d_ws;
  size_t off = 0;
  auto carve = [&](size_t bytes) -> char* {
    char* p = w + off;
    off = (off + bytes + 255) & ~(size_t)255;
    return p;
  };
  int* rowptr = (int*)carve(((size_t)N + 1) * 4);
  int* cursor = (int*)carve((size_t)N * 4);
  int* bsum = (int*)carve(64 * 4);
  u32* pe = (u32*)carve((size_t)E * 4);
  u16* Wcb = (u16*)carve((size_t)L * 65536 * 2);
  u16* layer0 = (u16*)carve((size_t)NP * 512);
  u16* bufA = (u16*)carve((size_t)NP * 512);
  u16* bufB = (u16*)carve((size_t)NP * 512);
  u16* suppt = (u16*)carve((size_t)NP * 512);
  float* g = (float*)carve((size_t)NP * 40);
  u16* W1b = (u16*)carve((size_t)NP * 512);

  int nb4 = (N + 3) / 4;
  int nbE = (E + 255) / 256;
  int nb1024 = (N + 1023) / 1024;

  // CSR build (parallel scan)
  (void)hipMemsetAsync(cursor, 0, (size_t)N * 4, stream);
  hist_kernel<<<nbE, 256, 0, stream>>>(rows, cursor, E);
  scanA_kernel<<<nb1024, 1024, 0, stream>>>(cursor, bsum, N);
  scanB_kernel<<<1, 64, 0, stream>>>(bsum, nb1024, rowptr + N);
  scanC_kernel<<<(N + 255) / 256, 256, 0, stream>>>(cursor, bsum, rowptr, N);
  scatter_kernel<<<nbE, 256, 0, stream>>>(rows, cols, ew, cursor, pe, E);

  // weight conversions
  cvt_wc_kernel<<<(L * 65536 + 255) / 256, 256, 0, stream>>>(Wc, Wcb, L * 65536);
  cvt_w1_kernel<<<dim3((N * 8 + 255) / 256, 8), 256, 0, stream>>>(W1, W1b, N, N32);

  // layer1
  spmm1_kernel<<<dim3(nb4, 8), 256, 0, stream>>>(rowptr, pe, W1b, layer0, N, N32);

  // 8 GCNII layers
  const u16* hin = layer0;
  int half = L / 2;
  for (int i = 0; i < L; ++i) {
    const u16* anchor = (i <= half) ? hin : layer0;
    spmm_blend_kernel<<<dim3(nb4, 8), 256, 0, stream>>>(rowptr, pe, hin, anchor, suppt, N, N32);
    u16* hout = (hin == bufA) ? bufB : ((hin == bufB) ? bufA : bufB);
    gemm_kernel<<<NP / 64, 128, 0, stream>>>(suppt, Wcb + (size_t)i * 65536, hout, N32);
    hin = hout;
  }

  // layer2
  gemm2_kernel<<<(N * 10 + 255) / 256, 256, 0, stream>>>(hin, W2, g, N, N32);
  spmm_final_kernel<<<nb4, 256, 0, stream>>>(rowptr, pe, g, out, N);
}

// Round 3
// 1635.941 us; speedup vs baseline: 1.9066x; 1.9066x over previous
//
#include <hip/hip_runtime.h>
#include <cmath>

typedef __attribute__((ext_vector_type(8))) short short8v;
typedef __attribute__((ext_vector_type(4))) float float4v;
typedef __attribute__((ext_vector_type(4))) unsigned int u32x4;
typedef unsigned short u16;
typedef unsigned int u32;

__device__ __forceinline__ u16 f2b(float f) {
  union { float f; u32 u; } v; v.f = f;
  return (u16)((v.u + 0x7fffu + ((v.u >> 16) & 1u)) >> 16);
}
__device__ __forceinline__ float b2f(u16 s) {
  union { u32 u; float f; } v; v.u = ((u32)s) << 16; return v.f;
}
__device__ __forceinline__ float lo_f(u32 u) {
  union { u32 u; float f; } v; v.u = u << 16; return v.f;
}
__device__ __forceinline__ float hi_f(u32 u) {
  union { u32 u; float f; } v; v.u = u & 0xffff0000u; return v.f;
}

// ---------------- CSR build ----------------
__global__ __launch_bounds__(256) void hist_kernel(const int* __restrict__ rows,
                                                   int* __restrict__ cnt, int E) {
  int i = blockIdx.x * 256 + threadIdx.x;
  if (i < E) atomicAdd(&cnt[rows[i]], 1);
}

__global__ __launch_bounds__(1024) void scanA_kernel(int* __restrict__ data,
                                                     int* __restrict__ bsum, int n) {
  __shared__ int sd[1024];
  int tid = threadIdx.x;
  int i = blockIdx.x * 1024 + tid;
  int v = (i < n) ? data[i] : 0;
  sd[tid] = v;
  __syncthreads();
  for (int o = 1; o < 1024; o <<= 1) {
    int t = (tid >= o) ? sd[tid - o] : 0;
    __syncthreads();
    sd[tid] += t;
    __syncthreads();
  }
  if (i < n) data[i] = sd[tid] - v;
  if (tid == 1023) bsum[blockIdx.x] = sd[1023];
}

__global__ __launch_bounds__(64) void scanB_kernel(int* __restrict__ bsum, int nb,
                                                   int* __restrict__ total_out) {
  int lane = threadIdx.x;
  int v = (lane < nb) ? bsum[lane] : 0;
  int orig = v;
  for (int o = 1; o < 64; o <<= 1) {
    int t = __shfl_up(v, o, 64);
    if (lane >= o) v += t;
  }
  if (lane < nb) bsum[lane] = v - orig;
  if (lane == 63) *total_out = v;
}

__global__ __launch_bounds__(256) void scanC_kernel(int* __restrict__ cursor,
                                                    const int* __restrict__ bsum,
                                                    int* __restrict__ rowptr, int n) {
  int i = blockIdx.x * 256 + threadIdx.x;
  if (i >= n) return;
  int val = cursor[i] + bsum[i >> 10];
  rowptr[i] = val;
  cursor[i] = val;
}

__global__ __launch_bounds__(256) void scatter_kernel(const int* __restrict__ rows,
                                                      const int* __restrict__ cols,
                                                      const float* __restrict__ ew,
                                                      int* __restrict__ cursor,
                                                      u32* __restrict__ pe, int E) {
  int i = blockIdx.x * 256 + threadIdx.x;
  if (i >= E) return;
  int p = atomicAdd(&cursor[rows[i]], 1);
  u32 wq = (u32)(ew[i] * 65536.0f);
  if (wq > 65535u) wq = 65535u;
  pe[p] = (wq << 16) | (u32)cols[i];
}

// ---------------- conversions ----------------
// W1 [N,256] f32 -> bf16 row-major [NP][256]
__global__ __launch_bounds__(256) void cvt_w1_kernel(const float* __restrict__ in,
                                                     u16* __restrict__ outb, long n4) {
  long i = (long)blockIdx.x * 256 + threadIdx.x;
  if (i >= n4) return;
  float4 v = ((const float4*)in)[i];
  ushort4 r; r.x = f2b(v.x); r.y = f2b(v.y); r.z = f2b(v.z); r.w = f2b(v.w);
  ((ushort4*)outb)[i] = r;
}

// B'[l][n][k] = bf16( theta_l * Wc[l][k][n] + (1-theta_l)*(k==n) )  via LDS transpose
__global__ __launch_bounds__(256) void cvt_wc_kernel(const float* __restrict__ in,
                                                     u16* __restrict__ outb) {
  __shared__ u16 t[64][68];
  int l = blockIdx.z;
  int k0 = blockIdx.y << 6, n0 = blockIdx.x << 6;
  float theta = logf(0.1f / (float)(l + 1) + 1.0f);
  float omt = 1.0f - theta;
  int kk = threadIdx.x >> 2;
  int nq = (threadIdx.x & 3) << 4;
  const float* ip = in + ((size_t)l << 16) + ((size_t)(k0 + kk) << 8) + n0 + nq;
  int gk = k0 + kk;
#pragma unroll
  for (int q = 0; q < 16; q += 4) {
    float4 v = *(const float4*)(ip + q);
    float fv[4] = {v.x, v.y, v.z, v.w};
#pragma unroll
    for (int x = 0; x < 4; ++x) {
      int gn = n0 + nq + q + x;
      float f = theta * fv[x];
      if (gk == gn) f += omt;
      t[nq + q + x][kk] = f2b(f);
    }
  }
  __syncthreads();
  int nn = threadIdx.x >> 2;
  int kq = (threadIdx.x & 3) << 4;
  u16* op = outb + ((size_t)l << 16) + ((size_t)(n0 + nn) << 8) + k0 + kq;
  u32x4 w0, w1;
#pragma unroll
  for (int x = 0; x < 4; ++x) {
    w0[x] = (u32)t[nn][kq + 2 * x] | ((u32)t[nn][kq + 2 * x + 1] << 16);
    w1[x] = (u32)t[nn][kq + 8 + 2 * x] | ((u32)t[nn][kq + 8 + 2 * x + 1] << 16);
  }
  *(u32x4*)op = w0;
  *(u32x4*)(op + 8) = w1;
}

// ---------------- SpMM (full 256-wide rows, 2 edges/iter, clamped unroll 4) ----------------
// half-wave h handles edges j2+h; lane owns 8 cols (16 B).
__global__ __launch_bounds__(256) void spmm1_kernel(const int* __restrict__ rowptr,
                                                    const u32* __restrict__ pe,
                                                    const u16* __restrict__ X,
                                                    u16* __restrict__ outb, int n) {
  int row = blockIdx.x * 4 + (threadIdx.x >> 6);
  if (row >= n) return;
  int lane = threadIdx.x & 63;
  int half = lane >> 5;
  int cq = lane & 31;
  int s = rowptr[row], e = rowptr[row + 1];
  float a[8] = {0, 0, 0, 0, 0, 0, 0, 0};
  for (int j2 = s; j2 < e; j2 += 8) {
#pragma unroll
    for (int u = 0; u < 4; ++u) {
      int j = j2 + 2 * u + half;
      int jc = (j < e) ? j : (e - 1);
      u32 p = __builtin_nontemporal_load(pe + jc);
      float wv = (float)(p >> 16) * (1.0f / 65536.0f);
      if (j >= e) wv = 0.f;
      u32x4 v = *(const u32x4*)(X + ((size_t)(p & 0xFFFFu) << 8) + (cq << 3));
#pragma unroll
      for (int q = 0; q < 4; ++q) {
        a[2 * q] = fmaf(wv, lo_f(v[q]), a[2 * q]);
        a[2 * q + 1] = fmaf(wv, hi_f(v[q]), a[2 * q + 1]);
      }
    }
  }
#pragma unroll
  for (int q = 0; q < 8; ++q) a[q] += __shfl_xor(a[q], 32);
  if (lane < 32) {
    u32x4 o;
#pragma unroll
    for (int q = 0; q < 4; ++q)
      o[q] = (u32)f2b(fmaxf(a[2 * q], 0.f)) | ((u32)f2b(fmaxf(a[2 * q + 1], 0.f)) << 16);
    __builtin_nontemporal_store(o, (u32x4*)(outb + ((size_t)row << 8) + (cq << 3)));
  }
}

__global__ __launch_bounds__(256) void spmm_blend_kernel(const int* __restrict__ rowptr,
                                                         const u32* __restrict__ pe,
                                                         const u16* __restrict__ X,
                                                         const u16* __restrict__ anchor,
                                                         u16* __restrict__ outb, int n) {
  int row = blockIdx.x * 4 + (threadIdx.x >> 6);
  if (row >= n) return;
  int lane = threadIdx.x & 63;
  int half = lane >> 5;
  int cq = lane & 31;
  int s = rowptr[row], e = rowptr[row + 1];
  float a[8] = {0, 0, 0, 0, 0, 0, 0, 0};
  for (int j2 = s; j2 < e; j2 += 8) {
#pragma unroll
    for (int u = 0; u < 4; ++u) {
      int j = j2 + 2 * u + half;
      int jc = (j < e) ? j : (e - 1);
      u32 p = __builtin_nontemporal_load(pe + jc);
      float wv = (float)(p >> 16) * (1.0f / 65536.0f);
      if (j >= e) wv = 0.f;
      u32x4 v = *(const u32x4*)(X + ((size_t)(p & 0xFFFFu) << 8) + (cq << 3));
#pragma unroll
      for (int q = 0; q < 4; ++q) {
        a[2 * q] = fmaf(wv, lo_f(v[q]), a[2 * q]);
        a[2 * q + 1] = fmaf(wv, hi_f(v[q]), a[2 * q + 1]);
      }
    }
  }
#pragma unroll
  for (int q = 0; q < 8; ++q) a[q] += __shfl_xor(a[q], 32);
  if (lane < 32) {
    size_t off = ((size_t)row << 8) + (cq << 3);
    u32x4 av = __builtin_nontemporal_load((const u32x4*)(anchor + off));
    u32x4 o;
#pragma unroll
    for (int q = 0; q < 4; ++q) {
      float r0 = 0.9f * a[2 * q] + 0.1f * lo_f(av[q]);
      float r1 = 0.9f * a[2 * q + 1] + 0.1f * hi_f(av[q]);
      o[q] = (u32)f2b(r0) | ((u32)f2b(r1) << 16);
    }
    __builtin_nontemporal_store(o, (u32x4*)(outb + off));
  }
}

// ---------------- dense GEMM: Hout = relu(A @ B'), row-major, LDS epilogue ----------------
__global__ __launch_bounds__(128) void gemm_kernel(const u16* __restrict__ A,
                                                   const u16* __restrict__ B,
                                                   u16* __restrict__ Hout) {
  __shared__ u16 tile[64 * 264];
  int wave = threadIdx.x >> 6;
  int lane = threadIdx.x & 63;
  int m0 = blockIdx.x * 64 + wave * 32;
  int r0 = m0 + (lane & 15);
  int khalf = (lane >> 4) << 3;
  const u16* Ap = A + ((size_t)r0 << 8) + khalf;
  const u16* Bp = B + ((lane & 15) << 8) + khalf;

  float4v acc0[16], acc1[16];
#pragma unroll
  for (int i = 0; i < 16; ++i) {
    acc0[i] = (float4v){0.f, 0.f, 0.f, 0.f};
    acc1[i] = (float4v){0.f, 0.f, 0.f, 0.f};
  }
#pragma unroll
  for (int ks = 0; ks < 8; ++ks) {
    short8v a0 = *(const short8v*)(Ap + (ks << 5));
    short8v a1 = *(const short8v*)(Ap + 4096 + (ks << 5));
#pragma unroll
    for (int nf = 0; nf < 16; ++nf) {
      short8v b = *(const short8v*)(Bp + (nf << 12) + (ks << 5));
      acc0[nf] = __builtin_amdgcn_mfma_f32_16x16x32_bf16(a0, b, acc0[nf], 0, 0, 0);
      acc1[nf] = __builtin_amdgcn_mfma_f32_16x16x32_bf16(a1, b, acc1[nf], 0, 0, 0);
    }
  }
  int lrbase = wave * 32 + ((lane >> 4) << 2);
  int ccol = lane & 15;
#pragma unroll
  for (int nf = 0; nf < 16; ++nf) {
    int col = (nf << 4) + ccol;
#pragma unroll
    for (int j = 0; j < 4; ++j) {
      tile[(lrbase + j) * 264 + col] = f2b(fmaxf(acc0[nf][j], 0.f));
      tile[(lrbase + j + 16) * 264 + col] = f2b(fmaxf(acc1[nf][j], 0.f));
    }
  }
  __syncthreads();
#pragma unroll
  for (int it = 0; it < 16; ++it) {
    int idx = it * 128 + threadIdx.x;
    int lr = idx >> 5;
    int ch = idx & 31;
    u32x4 v = *(const u32x4*)(tile + lr * 264 + (ch << 3));
    __builtin_nontemporal_store(
        v, (u32x4*)(Hout + (((size_t)blockIdx.x * 64 + lr) << 8) + (ch << 3)));
  }
}

// ---------------- h @ W2 (256 -> 10) ----------------
__global__ __launch_bounds__(256) void gemm2_kernel(const u16* __restrict__ Hb,
                                                    const float* __restrict__ W2,
                                                    float* __restrict__ g, int n) {
  __shared__ float sW2[2560];
  for (int i = threadIdx.x; i < 2560; i += 256) sW2[i] = W2[i];
  __syncthreads();
  int idx = blockIdx.x * 256 + threadIdx.x;
  if (idx >= n * 10) return;
  int r = idx / 10, c = idx - r * 10;
  const u16* hp = Hb + ((size_t)r << 8);
  float acc = 0.f;
  for (int k = 0; k < 256; k += 8) {
    u32x4 v = *(const u32x4*)(hp + k);
#pragma unroll
    for (int q = 0; q < 4; ++q) {
      acc = fmaf(lo_f(v[q]), sW2[(k + 2 * q) * 10 + c], acc);
      acc = fmaf(hi_f(v[q]), sW2[(k + 2 * q + 1) * 10 + c], acc);
    }
  }
  g[idx] = acc;
}

// ---------------- final SpMM on [N,10] f32 (6 edges/iter, clamped unroll 4) ----------------
__global__ __launch_bounds__(256) void spmm_final_kernel(const int* __restrict__ rowptr,
                                                         const u32* __restrict__ pe,
                                                         const float* __restrict__ g,
                                                         float* __restrict__ out, int n) {
  int row = blockIdx.x * 4 + (threadIdx.x >> 6);
  if (row >= n) return;
  int lane = threadIdx.x & 63;
  int es = lane / 10;
  int c = lane - es * 10;
  bool active = lane < 60;
  int s = rowptr[row], e = rowptr[row + 1];
  float acc = 0.f;
  for (int j6 = s; j6 < e; j6 += 24) {
#pragma unroll
    for (int u = 0; u < 4; ++u) {
      int j = j6 + 6 * u + es;
      int jc = (j < e) ? j : (e - 1);
      u32 p = __builtin_nontemporal_load(pe + jc);
      float wv = (float)(p >> 16) * (1.0f / 65536.0f);
      if (!active || j >= e) wv = 0.f;
      acc = fmaf(wv, g[(size_t)(p & 0xFFFFu) * 10 + c], acc);
    }
  }
  float a0 = acc;
  acc = a0 + __shfl(a0, lane + 10, 64) + __shfl(a0, lane + 20, 64) +
        __shfl(a0, lane + 30, 64) + __shfl(a0, lane + 40, 64) + __shfl(a0, lane + 50, 64);
  if (lane < 10) out[(size_t)row * 10 + lane] = acc;
}

extern "C" void kernel_launch(void* const* d_in, const int* in_sizes, int n_in,
                              void* d_out, int out_size, void* d_ws, size_t ws_size,
                              hipStream_t stream) {
  const int* rows = (const int*)d_in[1];
  const int* cols = (const int*)d_in[2];
  const float* ew = (const float*)d_in[3];
  const float* W1 = (const float*)d_in[4];
  const float* Wc = (const float*)d_in[5];
  const float* W2 = (const float*)d_in[6];
  float* out = (float*)d_out;
  const int N = in_sizes[0];
  const int E = in_sizes[1];
  const int L = in_sizes[5] >> 16;
  const int NP = ((N + 127) / 128) * 128;

  char* w = (char*)d_ws;
  size_t off = 0;
  auto carve = [&](size_t bytes) -> char* {
    char* p = w + off;
    off = (off + bytes + 255) & ~(size_t)255;
    return p;
  };
  int* rowptr = (int*)carve(((size_t)N + 1) * 4);
  int* cursor = (int*)carve((size_t)N * 4);
  int* bsum = (int*)carve(64 * 4);
  u32* pe = (u32*)carve((size_t)E * 4);
  u16* Wcb = (u16*)carve((size_t)L * 65536 * 2);
  u16* layer0 = (u16*)carve((size_t)NP * 512);
  u16* bufA = (u16*)carve((size_t)NP * 512);
  u16* bufB = (u16*)carve((size_t)NP * 512);
  u16* suppt = (u16*)carve((size_t)NP * 512);
  float* g = (float*)carve((size_t)NP * 40);
  u16* W1b = (u16*)carve((size_t)NP * 512);

  int nb4 = (N + 3) / 4;
  int nbE = (E + 255) / 256;
  int nb1024 = (N + 1023) / 1024;

  // CSR build
  (void)hipMemsetAsync(cursor, 0, (size_t)N * 4, stream);
  hist_kernel<<<nbE, 256, 0, stream>>>(rows, cursor, E);
  scanA_kernel<<<nb1024, 1024, 0, stream>>>(cursor, bsum, N);
  scanB_kernel<<<1, 64, 0, stream>>>(bsum, nb1024, rowptr + N);
  scanC_kernel<<<(N + 255) / 256, 256, 0, stream>>>(cursor, bsum, rowptr, N);
  scatter_kernel<<<nbE, 256, 0, stream>>>(rows, cols, ew, cursor, pe, E);

  // weight conversions
  cvt_wc_kernel<<<dim3(4, 4, L), 256, 0, stream>>>(Wc, Wcb);
  {
    long n4 = (long)N * 64;
    cvt_w1_kernel<<<(int)((n4 + 255) / 256), 256, 0, stream>>>(W1, W1b, n4);
  }

  // layer1
  spmm1_kernel<<<nb4, 256, 0, stream>>>(rowptr, pe, W1b, layer0, N);

  // 8 GCNII layers
  const u16* hin = layer0;
  int half = L / 2;
  for (int i = 0; i < L; ++i) {
    const u16* anchor = (i <= half) ? hin : layer0;
    spmm_blend_kernel<<<nb4, 256, 0, stream>>>(rowptr, pe, hin, anchor, suppt, N);
    u16* hout = (hin == bufA) ? bufB : ((hin == bufB) ? bufA : bufB);
    gemm_kernel<<<NP / 64, 128, 0, stream>>>(suppt, Wcb + (size_t)i * 65536, hout);
    hin = hout;
  }

  // layer2
  gemm2_kernel<<<(N * 10 + 255) / 256, 256, 0, stream>>>(hin, W2, g, N);
  spmm_final_kernel<<<nb4, 256, 0, stream>>>(rowptr, pe, g, out, N);
}